// Round 6
// baseline (84.427 us; speedup 1.0000x reference)
//
#include <hip/hip_runtime.h>
#include <hip/hip_bf16.h>

// Problem constants (from reference setup_inputs)
#define BDIM 256     // batch
#define NDIM 1152    // route nodes
#define CIN 8
#define KDIM 10      // num capsule groups
#define COUT 16
#define NTHREADS 1024
#define BT 2         // batches per block -> W[k] read once per 2 b's
#define NPT 9        // n values per thread = NDIM / 128

// Block = (k, b-pair), 1024 threads (16 waves) -> 2 blocks/CU = 32 waves/CU.
// Thread t owns co-PAIR cop = t&7 (co = 2*cop, 2*cop+1) at n = (t>>3) + 128j.
// W loads: float2, 8 cop-lanes cover each 64B line exactly once.
// pred in LDS as bf16x2: uint2 per (n,cop) = {b0:c0c1, b1:c0c1}; byte addr
// = 8*lane -> conflict-free ds_write_b64/ds_read_b64.
// No max-subtraction in softmax: |p*vc| << 88, ratio sp/se unchanged.
// Per-thread state kept < 64 VGPR (launch_bounds(1024,8)) so nothing spills.

__device__ __forceinline__ unsigned pack2(float a, float b) {   // v_cvt_pk_bf16_f32
    union { __hip_bfloat162 h; unsigned u; } cv;
    cv.h = __float22bfloat162_rn(make_float2(a, b));
    return cv.u;
}
__device__ __forceinline__ float bf_lo(unsigned u) { return __uint_as_float(u << 16); }
__device__ __forceinline__ float bf_hi(unsigned u) { return __uint_as_float(u & 0xffff0000u); }

__global__ __launch_bounds__(NTHREADS, 8)
void capsule_routing_kernel(const float* __restrict__ x,      // [B, N, CIN]
                            const float* __restrict__ w,      // [K, N, CIN, COUT]
                            const int*   __restrict__ niter_p,
                            float*       __restrict__ out)    // [K, B, COUT]
{
    __shared__ uint2  predS[NDIM * 8];     // [n][cop], bf16x2 x2, 73728 B
    __shared__ float4 red[16][8][2];       // [wv][cop][{4 sums, 4 sums}], 4096 B

    const int blk = blockIdx.x;
    const int k   = blk >> 7;              // / (BDIM/BT) == 128
    const int b0  = (blk & 127) * BT;
    const int t   = threadIdx.x;
    const int wv  = t >> 6;
    const int l   = t & 63;
    const int cop = t & 7;                 // co pair: co = 2*cop, 2*cop+1
    const int nb  = t >> 3;                // base n (0..127)

    const float* __restrict__ xb0 = x + (size_t)b0 * NDIM * CIN;
    const float* __restrict__ xb1 = xb0 + NDIM * CIN;
    const float* __restrict__ wk  = w + (size_t)k * NDIM * CIN * COUT + cop * 2;

    // per-thread partial sums: [b][c] for c in {co0, co1}
    float ps00 = 0.f, ps01 = 0.f, ps10 = 0.f, ps11 = 0.f;

    // -------- Phase 1: pred for both batches + fused per-thread sum --------
#pragma unroll 1
    for (int j = 0; j < NPT; ++j) {
        const int n = nb + 128 * j;
        const float4 xa0 = *reinterpret_cast<const float4*>(xb0 + n * CIN);
        const float4 xc0 = *reinterpret_cast<const float4*>(xb0 + n * CIN + 4);
        const float4 xa1 = *reinterpret_cast<const float4*>(xb1 + n * CIN);
        const float4 xc1 = *reinterpret_cast<const float4*>(xb1 + n * CIN + 4);
        const float xs0[8] = {xa0.x,xa0.y,xa0.z,xa0.w,xc0.x,xc0.y,xc0.z,xc0.w};
        const float xs1[8] = {xa1.x,xa1.y,xa1.z,xa1.w,xc1.x,xc1.y,xc1.z,xc1.w};
        const float* wr = wk + (size_t)n * (CIN * COUT);
        float a00 = 0.f, a01 = 0.f, a10 = 0.f, a11 = 0.f;
#pragma unroll
        for (int i = 0; i < CIN; ++i) {
            const float2 w2 = *reinterpret_cast<const float2*>(wr + i * COUT);
            a00 = fmaf(xs0[i], w2.x, a00);
            a01 = fmaf(xs0[i], w2.y, a01);
            a10 = fmaf(xs1[i], w2.x, a10);
            a11 = fmaf(xs1[i], w2.y, a11);
        }
        uint2 qq;
        qq.x = pack2(a00, a01);
        qq.y = pack2(a10, a11);
        predS[n * 8 + cop] = qq;           // ds_write_b64, addr = 8*lane
        ps00 += a00; ps01 += a01; ps10 += a10; ps11 += a11;
    }

    // intra-wave reduce over the 8 lanes sharing cop (lane bits 3..5)
#pragma unroll
    for (int m = 8; m < 64; m <<= 1) {
        ps00 += __shfl_xor(ps00, m, 64);
        ps01 += __shfl_xor(ps01, m, 64);
        ps10 += __shfl_xor(ps10, m, 64);
        ps11 += __shfl_xor(ps11, m, 64);
    }
    if (l < 8)                              // lane l holds cop == l
        red[wv][l][0] = make_float4(ps00, ps01, ps10, ps11);
    __syncthreads();
    float sT00 = 0.f, sT01 = 0.f, sT10 = 0.f, sT11 = 0.f;
#pragma unroll 4
    for (int wvi = 0; wvi < 16; ++wvi) {
        const float4 r = red[wvi][cop][0];
        sT00 += r.x; sT01 += r.y; sT10 += r.z; sT11 += r.w;
    }

    const int niter = *niter_p;

    // Iteration 1: logits == 0 -> uniform softmax -> s = mean_n(pred)
    float v00, v01, v10, v11, vc00, vc01, vc10, vc11;
    {
        const float inv = 1.0f / (float)NDIM;
        const float s00 = sT00 * inv, s01 = sT01 * inv;
        const float s10 = sT10 * inv, s11 = sT11 * inv;
        v00 = s00 * fabsf(s00) / (1.f + s00 * s00);   // squash (singleton dim)
        v01 = s01 * fabsf(s01) / (1.f + s01 * s01);
        v10 = s10 * fabsf(s10) / (1.f + s10 * s10);
        v11 = s11 * fabsf(s11) / (1.f + s11 * s11);
        vc00 = v00; vc01 = v01; vc10 = v10; vc11 = v11;
    }

    for (int it = 1; it < niter; ++it) {
        float se00 = 0.f, se01 = 0.f, se10 = 0.f, se11 = 0.f;
        float sp00 = 0.f, sp01 = 0.f, sp10 = 0.f, sp11 = 0.f;
#pragma unroll 3
        for (int j = 0; j < NPT; ++j) {
            const int n = nb + 128 * j;
            const uint2 q = predS[n * 8 + cop];    // ds_read_b64, conflict-free
            const float p00 = bf_lo(q.x), p01 = bf_hi(q.x);
            const float p10 = bf_lo(q.y), p11 = bf_hi(q.y);
            const float e00 = __expf(p00 * vc00);  // no max-sub needed
            const float e01 = __expf(p01 * vc01);
            const float e10 = __expf(p10 * vc10);
            const float e11 = __expf(p11 * vc11);
            se00 += e00; sp00 = fmaf(e00, p00, sp00);
            se01 += e01; sp01 = fmaf(e01, p01, sp01);
            se10 += e10; sp10 = fmaf(e10, p10, sp10);
            se11 += e11; sp11 = fmaf(e11, p11, sp11);
        }
#pragma unroll
        for (int m = 8; m < 64; m <<= 1) {
            se00 += __shfl_xor(se00, m, 64);
            se01 += __shfl_xor(se01, m, 64);
            se10 += __shfl_xor(se10, m, 64);
            se11 += __shfl_xor(se11, m, 64);
            sp00 += __shfl_xor(sp00, m, 64);
            sp01 += __shfl_xor(sp01, m, 64);
            sp10 += __shfl_xor(sp10, m, 64);
            sp11 += __shfl_xor(sp11, m, 64);
        }
        __syncthreads();   // previous readers of red done before overwrite
        if (l < 8) {
            red[wv][l][0] = make_float4(se00, se01, se10, se11);
            red[wv][l][1] = make_float4(sp00, sp01, sp10, sp11);
        }
        __syncthreads();
        float seT00 = 0.f, seT01 = 0.f, seT10 = 0.f, seT11 = 0.f;
        float spT00 = 0.f, spT01 = 0.f, spT10 = 0.f, spT11 = 0.f;
#pragma unroll 4
        for (int wvi = 0; wvi < 16; ++wvi) {
            const float4 a = red[wvi][cop][0];
            const float4 b = red[wvi][cop][1];
            seT00 += a.x; seT01 += a.y; seT10 += a.z; seT11 += a.w;
            spT00 += b.x; spT01 += b.y; spT10 += b.z; spT11 += b.w;
        }
        const float s00 = spT00 / seT00, s01 = spT01 / seT01;
        const float s10 = spT10 / seT10, s11 = spT11 / seT11;
        v00 = s00 * fabsf(s00) / (1.f + s00 * s00);
        v01 = s01 * fabsf(s01) / (1.f + s01 * s01);
        v10 = s10 * fabsf(s10) / (1.f + s10 * s10);
        v11 = s11 * fabsf(s11) / (1.f + s11 * s11);
        vc00 += v00; vc01 += v01; vc10 += v10; vc11 += v11;
    }

    if (t < 8) {   // cop == t: 8 lanes x float2 = 64B coalesced per batch
        *reinterpret_cast<float2*>(out + ((size_t)k * BDIM + b0)     * COUT + t * 2) =
            make_float2(v00, v01);
        *reinterpret_cast<float2*>(out + ((size_t)k * BDIM + b0 + 1) * COUT + t * 2) =
            make_float2(v10, v11);
    }
}

extern "C" void kernel_launch(void* const* d_in, const int* in_sizes, int n_in,
                              void* d_out, int out_size, void* d_ws, size_t ws_size,
                              hipStream_t stream) {
    const float* x = (const float*)d_in[0];
    const float* w = (const float*)d_in[1];
    const int* niter = (const int*)d_in[2];
    float* out = (float*)d_out;

    const int grid = KDIM * (BDIM / BT);   // 1280 blocks, k outer
    capsule_routing_kernel<<<grid, NTHREADS, 0, stream>>>(x, w, niter, out);
}

// Round 7
// 70.191 us; speedup vs baseline: 1.2028x; 1.2028x over previous
//
#include <hip/hip_runtime.h>
#include <hip/hip_bf16.h>

// Problem constants (from reference setup_inputs)
#define BDIM 256     // batch
#define NDIM 1152    // route nodes
#define CIN 8
#define KDIM 10      // num capsule groups
#define COUT 16
#define NTHREADS 512
#define BT 2         // batches per block -> W[k] read once per 2 b's
#define NPT 9        // n values per thread = NDIM / (NTHREADS/4)

// Block = (k, b-pair). Thread t owns co-quad coq=t&3 at n = (t>>2)+128j.
// pred kept as bf16x2 in LDS, uint4 per (n,coq) -> single ds_read/write_b128
// at byte addr 16*lane (conflict-free). W loads: float4, 4 coq-lanes cover
// each 64B line exactly once. No max-subtraction in softmax (|p*vc| << 88).
//
// Occupancy pinning: LDS (78.8 KB) caps us at 2 blocks/CU = 4 waves/EU.
// amdgpu_waves_per_eu(4,4) tells the allocator to target EXACTLY that, giving
// it the full 128-VGPR budget -- launch_bounds(512,4) only sets a minimum and
// the allocator previously aimed for 8 waves/EU (64 VGPR) and spilled
// (R5: WRITE_SIZE 31 MB of scratch traffic).

#if defined(__has_builtin)
#  if __has_builtin(__builtin_amdgcn_exp2f)
#    define EXP2F(x) __builtin_amdgcn_exp2f(x)
#  endif
#endif
#ifndef EXP2F
#  define EXP2F(x) exp2f(x)
#endif
#define LOG2E 1.4426950408889634f

__device__ __forceinline__ unsigned pack2(float a, float b) {   // v_cvt_pk_bf16_f32
    union { __hip_bfloat162 h; unsigned u; } cv;
    cv.h = __float22bfloat162_rn(make_float2(a, b));
    return cv.u;
}
__device__ __forceinline__ float bf_lo(unsigned u) { return __uint_as_float(u << 16); }
__device__ __forceinline__ float bf_hi(unsigned u) { return __uint_as_float(u & 0xffff0000u); }

__global__ __attribute__((amdgpu_flat_work_group_size(NTHREADS, NTHREADS),
                          amdgpu_waves_per_eu(4, 4)))
void capsule_routing_kernel(const float* __restrict__ x,      // [B, N, CIN]
                            const float* __restrict__ w,      // [K, N, CIN, COUT]
                            const int*   __restrict__ niter_p,
                            float*       __restrict__ out)    // [K, B, COUT]
{
    __shared__ uint4  predS[NDIM * 4];     // [n][coq] = {b0c01,b0c23,b1c01,b1c23}, 73728 B
    __shared__ float4 redP[8][4][2];       // [wv][coq][bb] psum, 1 KB
    __shared__ float4 redI[2][8][4][4];    // [buf][wv][coq][{se0,sp0,se1,sp1}], 4 KB

    const int blk = blockIdx.x;
    const int k   = blk >> 7;              // / (BDIM/BT) == 128
    const int b0  = (blk & 127) * BT;
    const int t   = threadIdx.x;
    const int wv  = t >> 6;
    const int l   = t & 63;
    const int coq = t & 3;                 // co = coq*4 .. coq*4+3
    const int nb  = t >> 2;                // base n (0..127)

    const float* __restrict__ xb0 = x + (size_t)b0 * NDIM * CIN;
    const float* __restrict__ xb1 = xb0 + NDIM * CIN;
    const float* __restrict__ wk  = w + (size_t)k * NDIM * CIN * COUT + coq * 4;

    float ps0[4] = {0.f,0.f,0.f,0.f}, ps1[4] = {0.f,0.f,0.f,0.f};

    // -------- Phase 1: pred for both batches + fused per-thread sum --------
#pragma unroll 3
    for (int j = 0; j < NPT; ++j) {
        const int n = nb + 128 * j;
        const float4 xa0 = *reinterpret_cast<const float4*>(xb0 + n * CIN);
        const float4 xc0 = *reinterpret_cast<const float4*>(xb0 + n * CIN + 4);
        const float4 xa1 = *reinterpret_cast<const float4*>(xb1 + n * CIN);
        const float4 xc1 = *reinterpret_cast<const float4*>(xb1 + n * CIN + 4);
        const float xs0[8] = {xa0.x,xa0.y,xa0.z,xa0.w,xc0.x,xc0.y,xc0.z,xc0.w};
        const float xs1[8] = {xa1.x,xa1.y,xa1.z,xa1.w,xc1.x,xc1.y,xc1.z,xc1.w};
        const float* wr = wk + (size_t)n * (CIN * COUT);
        float a0[4] = {0.f,0.f,0.f,0.f}, a1[4] = {0.f,0.f,0.f,0.f};
#pragma unroll
        for (int i = 0; i < CIN; ++i) {
            const float4 w4 = *reinterpret_cast<const float4*>(wr + i * COUT);
            a0[0] = fmaf(xs0[i], w4.x, a0[0]);
            a0[1] = fmaf(xs0[i], w4.y, a0[1]);
            a0[2] = fmaf(xs0[i], w4.z, a0[2]);
            a0[3] = fmaf(xs0[i], w4.w, a0[3]);
            a1[0] = fmaf(xs1[i], w4.x, a1[0]);
            a1[1] = fmaf(xs1[i], w4.y, a1[1]);
            a1[2] = fmaf(xs1[i], w4.z, a1[2]);
            a1[3] = fmaf(xs1[i], w4.w, a1[3]);
        }
        uint4 qq;
        qq.x = pack2(a0[0], a0[1]);
        qq.y = pack2(a0[2], a0[3]);
        qq.z = pack2(a1[0], a1[1]);
        qq.w = pack2(a1[2], a1[3]);
        predS[n * 4 + coq] = qq;           // ds_write_b128, addr = 16*lane
#pragma unroll
        for (int c = 0; c < 4; ++c) { ps0[c] += a0[c]; ps1[c] += a1[c]; }
    }

    // intra-wave reduce over the 16 lanes sharing coq
#pragma unroll
    for (int m = 4; m < 64; m <<= 1) {
#pragma unroll
        for (int c = 0; c < 4; ++c) {
            ps0[c] += __shfl_xor(ps0[c], m, 64);
            ps1[c] += __shfl_xor(ps1[c], m, 64);
        }
    }
    if (l < 4) {                            // lane l holds coq == l
        redP[wv][l][0] = make_float4(ps0[0], ps0[1], ps0[2], ps0[3]);
        redP[wv][l][1] = make_float4(ps1[0], ps1[1], ps1[2], ps1[3]);
    }
    __syncthreads();
    float sT0[4] = {0.f,0.f,0.f,0.f}, sT1[4] = {0.f,0.f,0.f,0.f};
#pragma unroll
    for (int wvi = 0; wvi < 8; ++wvi) {
        const float4 r0 = redP[wvi][coq][0];
        const float4 r1 = redP[wvi][coq][1];
        sT0[0] += r0.x; sT0[1] += r0.y; sT0[2] += r0.z; sT0[3] += r0.w;
        sT1[0] += r1.x; sT1[1] += r1.y; sT1[2] += r1.z; sT1[3] += r1.w;
    }

    const int niter = *niter_p;

    // Iteration 1: logits == 0 -> uniform softmax -> s = mean_n(pred)
    float v0[4], v1[4], vc0[4], vc1[4];
    {
        const float inv = 1.0f / (float)NDIM;
#pragma unroll
        for (int c = 0; c < 4; ++c) {
            const float s0 = sT0[c] * inv;
            const float s1 = sT1[c] * inv;
            v0[c] = s0 * fabsf(s0) / (1.f + s0 * s0);  // squash (singleton dim)
            v1[c] = s1 * fabsf(s1) / (1.f + s1 * s1);
            vc0[c] = v0[c];
            vc1[c] = v1[c];
        }
    }

    for (int it = 1; it < niter; ++it) {
        const int itb = it & 1;
        // fold log2(e) into vc once: exp(p*vc) == exp2(p * (vc*log2e))
        float vl0[4], vl1[4];
#pragma unroll
        for (int c = 0; c < 4; ++c) { vl0[c] = vc0[c] * LOG2E; vl1[c] = vc1[c] * LOG2E; }

        float se0[4]={0.f,0.f,0.f,0.f}, sp0[4]={0.f,0.f,0.f,0.f};
        float se1[4]={0.f,0.f,0.f,0.f}, sp1[4]={0.f,0.f,0.f,0.f};
#pragma unroll
        for (int j = 0; j < NPT; ++j) {
            const int n = nb + 128 * j;
            const uint4 q = predS[n * 4 + coq];   // ds_read_b128, conflict-free
            const float p0[4] = {bf_lo(q.x), bf_hi(q.x), bf_lo(q.y), bf_hi(q.y)};
            const float p1[4] = {bf_lo(q.z), bf_hi(q.z), bf_lo(q.w), bf_hi(q.w)};
#pragma unroll
            for (int c = 0; c < 4; ++c) {
                const float e0 = EXP2F(p0[c] * vl0[c]);   // bare v_exp_f32
                se0[c] += e0;
                sp0[c] = fmaf(e0, p0[c], sp0[c]);
                const float e1 = EXP2F(p1[c] * vl1[c]);
                se1[c] += e1;
                sp1[c] = fmaf(e1, p1[c], sp1[c]);
            }
        }
#pragma unroll
        for (int m = 4; m < 64; m <<= 1) {
#pragma unroll
            for (int c = 0; c < 4; ++c) {
                se0[c] += __shfl_xor(se0[c], m, 64);
                sp0[c] += __shfl_xor(sp0[c], m, 64);
                se1[c] += __shfl_xor(se1[c], m, 64);
                sp1[c] += __shfl_xor(sp1[c], m, 64);
            }
        }
        if (l < 4) {
            redI[itb][wv][l][0] = make_float4(se0[0], se0[1], se0[2], se0[3]);
            redI[itb][wv][l][1] = make_float4(sp0[0], sp0[1], sp0[2], sp0[3]);
            redI[itb][wv][l][2] = make_float4(se1[0], se1[1], se1[2], se1[3]);
            redI[itb][wv][l][3] = make_float4(sp1[0], sp1[1], sp1[2], sp1[3]);
        }
        __syncthreads();   // double-buffered redI: one barrier per iteration
        float seT0[4]={0.f,0.f,0.f,0.f}, spT0[4]={0.f,0.f,0.f,0.f};
        float seT1[4]={0.f,0.f,0.f,0.f}, spT1[4]={0.f,0.f,0.f,0.f};
#pragma unroll
        for (int wvi = 0; wvi < 8; ++wvi) {
            const float4 a = redI[itb][wvi][coq][0];
            const float4 b = redI[itb][wvi][coq][1];
            const float4 c4 = redI[itb][wvi][coq][2];
            const float4 d = redI[itb][wvi][coq][3];
            seT0[0]+=a.x; seT0[1]+=a.y; seT0[2]+=a.z; seT0[3]+=a.w;
            spT0[0]+=b.x; spT0[1]+=b.y; spT0[2]+=b.z; spT0[3]+=b.w;
            seT1[0]+=c4.x; seT1[1]+=c4.y; seT1[2]+=c4.z; seT1[3]+=c4.w;
            spT1[0]+=d.x; spT1[1]+=d.y; spT1[2]+=d.z; spT1[3]+=d.w;
        }
#pragma unroll
        for (int c = 0; c < 4; ++c) {
            const float s0 = spT0[c] / seT0[c];
            const float s1 = spT1[c] / seT1[c];
            v0[c] = s0 * fabsf(s0) / (1.f + s0 * s0);
            v1[c] = s1 * fabsf(s1) / (1.f + s1 * s1);
            vc0[c] += v0[c];
            vc1[c] += v1[c];
        }
    }

    if (t < 4) {   // coq == t
        float4 o0, o1;
        o0.x = v0[0]; o0.y = v0[1]; o0.z = v0[2]; o0.w = v0[3];
        o1.x = v1[0]; o1.y = v1[1]; o1.z = v1[2]; o1.w = v1[3];
        *reinterpret_cast<float4*>(out + ((size_t)k * BDIM + b0)     * COUT + t * 4) = o0;
        *reinterpret_cast<float4*>(out + ((size_t)k * BDIM + b0 + 1) * COUT + t * 4) = o1;
    }
}

extern "C" void kernel_launch(void* const* d_in, const int* in_sizes, int n_in,
                              void* d_out, int out_size, void* d_ws, size_t ws_size,
                              hipStream_t stream) {
    const float* x = (const float*)d_in[0];
    const float* w = (const float*)d_in[1];
    const int* niter = (const int*)d_in[2];
    float* out = (float*)d_out;

    const int grid = KDIM * (BDIM / BT);   // 1280 blocks, k outer
    capsule_routing_kernel<<<grid, NTHREADS, 0, stream>>>(x, w, niter, out);
}

// Round 8
// 65.844 us; speedup vs baseline: 1.2822x; 1.0660x over previous
//
#include <hip/hip_runtime.h>
#include <hip/hip_bf16.h>

// Problem constants (from reference setup_inputs)
#define BDIM 256     // batch
#define NDIM 1152    // route nodes
#define CIN 8
#define KDIM 10      // num capsule groups
#define COUT 16
#define NTHREADS 512
#define BT 2         // batches per block -> W[k] read once per 2 b's
#define NPT 9        // n values per thread = NDIM / (NTHREADS/4)

// Block = (k, b-pair). Thread t owns co-quad coq=t&3 at n = (t>>2)+128j.
// pred kept as bf16x2 in LDS, uint4 per (n,coq) -> single ds_read/write_b128
// at byte addr 16*lane (conflict-free). W loads: float4, 4 coq-lanes cover
// each 64B line exactly once. No max-subtraction in softmax (|p*vc| << 88).
//
// Spill control (R5/R7 lesson): phase-1 MUST be `unroll 1`. With unroll>=3
// the scheduler software-pipelines 3 iterations of float4 loads (~48 extra
// live VGPRs), blows the 64-reg budget, and spills ~25 MB to scratch
// (WRITE_SIZE 25-31 MB, +6 MB FETCH reloads). R6 proved unroll 1 -> 0 spill.
// TLP (16 waves/CU) hides the unpipelined load latency.

#if defined(__has_builtin)
#  if __has_builtin(__builtin_amdgcn_exp2f)
#    define EXP2F(x) __builtin_amdgcn_exp2f(x)
#  endif
#endif
#ifndef EXP2F
#  define EXP2F(x) exp2f(x)
#endif
#define LOG2E 1.4426950408889634f

__device__ __forceinline__ unsigned pack2(float a, float b) {   // v_cvt_pk_bf16_f32
    union { __hip_bfloat162 h; unsigned u; } cv;
    cv.h = __float22bfloat162_rn(make_float2(a, b));
    return cv.u;
}
__device__ __forceinline__ float bf_lo(unsigned u) { return __uint_as_float(u << 16); }
__device__ __forceinline__ float bf_hi(unsigned u) { return __uint_as_float(u & 0xffff0000u); }

__global__ __attribute__((amdgpu_flat_work_group_size(NTHREADS, NTHREADS),
                          amdgpu_waves_per_eu(4, 4)))
void capsule_routing_kernel(const float* __restrict__ x,      // [B, N, CIN]
                            const float* __restrict__ w,      // [K, N, CIN, COUT]
                            const int*   __restrict__ niter_p,
                            float*       __restrict__ out)    // [K, B, COUT]
{
    __shared__ uint4  predS[NDIM * 4];     // [n][coq] = {b0c01,b0c23,b1c01,b1c23}, 73728 B
    __shared__ float4 redP[8][4][2];       // [wv][coq][bb] psum, 1 KB
    __shared__ float4 redI[2][8][4][4];    // [buf][wv][coq][{se0,sp0,se1,sp1}], 4 KB

    const int blk = blockIdx.x;
    const int k   = blk >> 7;              // / (BDIM/BT) == 128
    const int b0  = (blk & 127) * BT;
    const int t   = threadIdx.x;
    const int wv  = t >> 6;
    const int l   = t & 63;
    const int coq = t & 3;                 // co = coq*4 .. coq*4+3
    const int nb  = t >> 2;                // base n (0..127)

    const float* __restrict__ xb0 = x + (size_t)b0 * NDIM * CIN;
    const float* __restrict__ xb1 = xb0 + NDIM * CIN;
    const float* __restrict__ wk  = w + (size_t)k * NDIM * CIN * COUT + coq * 4;

    float ps0[4] = {0.f,0.f,0.f,0.f}, ps1[4] = {0.f,0.f,0.f,0.f};

    // -------- Phase 1: pred for both batches + fused per-thread sum --------
#pragma unroll 1
    for (int j = 0; j < NPT; ++j) {
        const int n = nb + 128 * j;
        const float4 xa0 = *reinterpret_cast<const float4*>(xb0 + n * CIN);
        const float4 xc0 = *reinterpret_cast<const float4*>(xb0 + n * CIN + 4);
        const float4 xa1 = *reinterpret_cast<const float4*>(xb1 + n * CIN);
        const float4 xc1 = *reinterpret_cast<const float4*>(xb1 + n * CIN + 4);
        const float xs0[8] = {xa0.x,xa0.y,xa0.z,xa0.w,xc0.x,xc0.y,xc0.z,xc0.w};
        const float xs1[8] = {xa1.x,xa1.y,xa1.z,xa1.w,xc1.x,xc1.y,xc1.z,xc1.w};
        const float* wr = wk + (size_t)n * (CIN * COUT);
        float a0[4] = {0.f,0.f,0.f,0.f}, a1[4] = {0.f,0.f,0.f,0.f};
#pragma unroll
        for (int i = 0; i < CIN; ++i) {
            const float4 w4 = *reinterpret_cast<const float4*>(wr + i * COUT);
            a0[0] = fmaf(xs0[i], w4.x, a0[0]);
            a0[1] = fmaf(xs0[i], w4.y, a0[1]);
            a0[2] = fmaf(xs0[i], w4.z, a0[2]);
            a0[3] = fmaf(xs0[i], w4.w, a0[3]);
            a1[0] = fmaf(xs1[i], w4.x, a1[0]);
            a1[1] = fmaf(xs1[i], w4.y, a1[1]);
            a1[2] = fmaf(xs1[i], w4.z, a1[2]);
            a1[3] = fmaf(xs1[i], w4.w, a1[3]);
        }
        uint4 qq;
        qq.x = pack2(a0[0], a0[1]);
        qq.y = pack2(a0[2], a0[3]);
        qq.z = pack2(a1[0], a1[1]);
        qq.w = pack2(a1[2], a1[3]);
        predS[n * 4 + coq] = qq;           // ds_write_b128, addr = 16*lane
#pragma unroll
        for (int c = 0; c < 4; ++c) { ps0[c] += a0[c]; ps1[c] += a1[c]; }
    }

    // intra-wave reduce over the 16 lanes sharing coq
#pragma unroll
    for (int m = 4; m < 64; m <<= 1) {
#pragma unroll
        for (int c = 0; c < 4; ++c) {
            ps0[c] += __shfl_xor(ps0[c], m, 64);
            ps1[c] += __shfl_xor(ps1[c], m, 64);
        }
    }
    if (l < 4) {                            // lane l holds coq == l
        redP[wv][l][0] = make_float4(ps0[0], ps0[1], ps0[2], ps0[3]);
        redP[wv][l][1] = make_float4(ps1[0], ps1[1], ps1[2], ps1[3]);
    }
    __syncthreads();
    float sT0[4] = {0.f,0.f,0.f,0.f}, sT1[4] = {0.f,0.f,0.f,0.f};
#pragma unroll
    for (int wvi = 0; wvi < 8; ++wvi) {
        const float4 r0 = redP[wvi][coq][0];
        const float4 r1 = redP[wvi][coq][1];
        sT0[0] += r0.x; sT0[1] += r0.y; sT0[2] += r0.z; sT0[3] += r0.w;
        sT1[0] += r1.x; sT1[1] += r1.y; sT1[2] += r1.z; sT1[3] += r1.w;
    }

    const int niter = *niter_p;

    // Iteration 1: logits == 0 -> uniform softmax -> s = mean_n(pred)
    float v0[4], v1[4], vc0[4], vc1[4];
    {
        const float inv = 1.0f / (float)NDIM;
#pragma unroll
        for (int c = 0; c < 4; ++c) {
            const float s0 = sT0[c] * inv;
            const float s1 = sT1[c] * inv;
            v0[c] = s0 * fabsf(s0) / (1.f + s0 * s0);  // squash (singleton dim)
            v1[c] = s1 * fabsf(s1) / (1.f + s1 * s1);
            vc0[c] = v0[c];
            vc1[c] = v1[c];
        }
    }

    for (int it = 1; it < niter; ++it) {
        const int itb = it & 1;
        // fold log2(e) into vc once: exp(p*vc) == exp2(p * (vc*log2e))
        float vl0[4], vl1[4];
#pragma unroll
        for (int c = 0; c < 4; ++c) { vl0[c] = vc0[c] * LOG2E; vl1[c] = vc1[c] * LOG2E; }

        float se0[4]={0.f,0.f,0.f,0.f}, sp0[4]={0.f,0.f,0.f,0.f};
        float se1[4]={0.f,0.f,0.f,0.f}, sp1[4]={0.f,0.f,0.f,0.f};
#pragma unroll 3
        for (int j = 0; j < NPT; ++j) {
            const int n = nb + 128 * j;
            const uint4 q = predS[n * 4 + coq];   // ds_read_b128, conflict-free
            const float p0[4] = {bf_lo(q.x), bf_hi(q.x), bf_lo(q.y), bf_hi(q.y)};
            const float p1[4] = {bf_lo(q.z), bf_hi(q.z), bf_lo(q.w), bf_hi(q.w)};
#pragma unroll
            for (int c = 0; c < 4; ++c) {
                const float e0 = EXP2F(p0[c] * vl0[c]);   // bare v_exp_f32
                se0[c] += e0;
                sp0[c] = fmaf(e0, p0[c], sp0[c]);
                const float e1 = EXP2F(p1[c] * vl1[c]);
                se1[c] += e1;
                sp1[c] = fmaf(e1, p1[c], sp1[c]);
            }
        }
#pragma unroll
        for (int m = 4; m < 64; m <<= 1) {
#pragma unroll
            for (int c = 0; c < 4; ++c) {
                se0[c] += __shfl_xor(se0[c], m, 64);
                sp0[c] += __shfl_xor(sp0[c], m, 64);
                se1[c] += __shfl_xor(se1[c], m, 64);
                sp1[c] += __shfl_xor(sp1[c], m, 64);
            }
        }
        if (l < 4) {
            redI[itb][wv][l][0] = make_float4(se0[0], se0[1], se0[2], se0[3]);
            redI[itb][wv][l][1] = make_float4(sp0[0], sp0[1], sp0[2], sp0[3]);
            redI[itb][wv][l][2] = make_float4(se1[0], se1[1], se1[2], se1[3]);
            redI[itb][wv][l][3] = make_float4(sp1[0], sp1[1], sp1[2], sp1[3]);
        }
        __syncthreads();   // double-buffered redI: one barrier per iteration
        float seT0[4]={0.f,0.f,0.f,0.f}, spT0[4]={0.f,0.f,0.f,0.f};
        float seT1[4]={0.f,0.f,0.f,0.f}, spT1[4]={0.f,0.f,0.f,0.f};
#pragma unroll
        for (int wvi = 0; wvi < 8; ++wvi) {
            const float4 a = redI[itb][wvi][coq][0];
            const float4 b = redI[itb][wvi][coq][1];
            const float4 c4 = redI[itb][wvi][coq][2];
            const float4 d = redI[itb][wvi][coq][3];
            seT0[0]+=a.x; seT0[1]+=a.y; seT0[2]+=a.z; seT0[3]+=a.w;
            spT0[0]+=b.x; spT0[1]+=b.y; spT0[2]+=b.z; spT0[3]+=b.w;
            seT1[0]+=c4.x; seT1[1]+=c4.y; seT1[2]+=c4.z; seT1[3]+=c4.w;
            spT1[0]+=d.x; spT1[1]+=d.y; spT1[2]+=d.z; spT1[3]+=d.w;
        }
#pragma unroll
        for (int c = 0; c < 4; ++c) {
            const float s0 = spT0[c] / seT0[c];
            const float s1 = spT1[c] / seT1[c];
            v0[c] = s0 * fabsf(s0) / (1.f + s0 * s0);
            v1[c] = s1 * fabsf(s1) / (1.f + s1 * s1);
            vc0[c] += v0[c];
            vc1[c] += v1[c];
        }
    }

    if (t < 4) {   // coq == t
        float4 o0, o1;
        o0.x = v0[0]; o0.y = v0[1]; o0.z = v0[2]; o0.w = v0[3];
        o1.x = v1[0]; o1.y = v1[1]; o1.z = v1[2]; o1.w = v1[3];
        *reinterpret_cast<float4*>(out + ((size_t)k * BDIM + b0)     * COUT + t * 4) = o0;
        *reinterpret_cast<float4*>(out + ((size_t)k * BDIM + b0 + 1) * COUT + t * 4) = o1;
    }
}

extern "C" void kernel_launch(void* const* d_in, const int* in_sizes, int n_in,
                              void* d_out, int out_size, void* d_ws, size_t ws_size,
                              hipStream_t stream) {
    const float* x = (const float*)d_in[0];
    const float* w = (const float*)d_in[1];
    const int* niter = (const int*)d_in[2];
    float* out = (float*)d_out;

    const int grid = KDIM * (BDIM / BT);   // 1280 blocks, k outer
    capsule_routing_kernel<<<grid, NTHREADS, 0, stream>>>(x, w, niter, out);
}